// Round 11
// baseline (288.483 us; speedup 1.0000x reference)
//
#include <hip/hip_runtime.h>

typedef __bf16 bf16;
typedef __bf16 bf16x4 __attribute__((ext_vector_type(4)));
typedef __bf16 bf16x8 __attribute__((ext_vector_type(8)));
typedef float  f32x4  __attribute__((ext_vector_type(4)));

constexpr int Bb = 8, Ss = 1024, Dd = 1024, Hh = 16, HDd = 64;
constexpr int Mm = Bb * Ss;   // 8192
constexpr int Kk = 1024;

#define WAITV(n) asm volatile("s_waitcnt vmcnt(" #n ")" ::: "memory")
#define PHASE_BAR { __builtin_amdgcn_s_barrier(); __builtin_amdgcn_sched_barrier(0); }

// ---------------- fused cast f32 -> bf16 (5 segments, float4 chunks) ----------------
struct CastArgs {
  const float* src[5];
  bf16* dst[5];
  int cum[5];
};
__global__ void cast_all(CastArgs a, int tot) {
  int i = blockIdx.x * blockDim.x + threadIdx.x;
  if (i >= tot) return;
  int s, base;
  if (i < a.cum[0])      { s = 0; base = 0; }
  else if (i < a.cum[1]) { s = 1; base = a.cum[0]; }
  else if (i < a.cum[2]) { s = 2; base = a.cum[1]; }
  else if (i < a.cum[3]) { s = 3; base = a.cum[2]; }
  else                   { s = 4; base = a.cum[3]; }
  int j = i - base;
  float4 v = reinterpret_cast<const float4*>(a.src[s])[j];
  bf16x4 o = { (bf16)v.x, (bf16)v.y, (bf16)v.z, (bf16)v.w };
  reinterpret_cast<bf16x4*>(a.dst[s])[j] = o;
}

// ---------------- 128x128 2-barrier GEMM core (verified; used by gemm_out) ----------------
__device__ __forceinline__ void gemm_loop(const bf16* __restrict__ A, const bf16* __restrict__ Bm,
                                          int bm, int bn, unsigned char* As, unsigned char* Bs,
                                          int w, int lane, int l15, int g, f32x4 (&acc)[4][4]) {
  const bf16* srcA[4];
  const bf16* srcB[4];
#pragma unroll
  for (int i = 0; i < 4; ++i) {
    int gch = (w * 4 + i) * 64 + lane;  // chunk id 0..1023
    int r = gch >> 3, c = gch & 7, cs = c ^ (r & 7);
    srcA[i] = A  + (size_t)(bm * 128 + r) * Kk + cs * 8;
    srcB[i] = Bm + (size_t)(bn * 128 + r) * Kk + cs * 8;
  }
  for (int kt = 0; kt < Kk / 64; ++kt) {
    __syncthreads();
#pragma unroll
    for (int i = 0; i < 4; ++i) {
      __builtin_amdgcn_global_load_lds(
          (const __attribute__((address_space(1))) void*)(srcA[i] + kt * 64),
          (__attribute__((address_space(3))) void*)(As + (w * 4 + i) * 1024), 16, 0, 0);
      __builtin_amdgcn_global_load_lds(
          (const __attribute__((address_space(1))) void*)(srcB[i] + kt * 64),
          (__attribute__((address_space(3))) void*)(Bs + (w * 4 + i) * 1024), 16, 0, 0);
    }
    __syncthreads();
#pragma unroll
    for (int kk = 0; kk < 2; ++kk) {
      const int kb = kk * 64 + g * 16;
      bf16x8 af[4], bfr[4];
#pragma unroll
      for (int mi = 0; mi < 4; ++mi) {
        int row = ((w >> 1) * 64) + mi * 16 + l15;
        af[mi] = *reinterpret_cast<const bf16x8*>(As + row * 128 + (kb ^ ((row & 7) << 4)));
      }
#pragma unroll
      for (int ni = 0; ni < 4; ++ni) {
        int row = ((w & 1) * 64) + ni * 16 + l15;
        bfr[ni] = *reinterpret_cast<const bf16x8*>(Bs + row * 128 + (kb ^ ((row & 7) << 4)));
      }
#pragma unroll
      for (int mi = 0; mi < 4; ++mi)
#pragma unroll
        for (int ni = 0; ni < 4; ++ni)
          acc[mi][ni] = __builtin_amdgcn_mfma_f32_16x16x32_bf16(af[mi], bfr[ni], acc[mi][ni], 0, 0, 0);
    }
  }
}

// ---------------- QKV projection: 256x256 8-phase counted-vmcnt GEMM ----------------
// NT GEMM C[m][n] = A[m,:]·B[n,:], K=1024, 16 K-tiles of BK=64, 8 iterations x 8 phases.
// 8 waves (2M x 4N); per wave 8x4 16x16 fragments. LDS 128KB = 2 bufs x 4 units
// {A_k0,A_k1,B_k0,B_k1} of 16KB (256 rows x 64B, chunk-XOR swizzle (r&3)^((r>>2)&3)).
// Phase=(ksub,nhalf): 10 ds_read_b128 + 1 stage-unit issue + 16 MFMA (setprio-wrapped).
// vmcnt(8) at even-phase end (counted: 6 stage-ops max in flight, retire to 4); tail
// iteration drains (vmcnt(0)) at P4/P6 because its skipped stages break the steady count.
// Stage map per iter j (t0=2j buf0, t1=2j+1 buf1): P1:A_k1(t1) P2:B_k1(t1) P3:A_k0(t0+2)
// P4:B_k0(t0+2) P5:A_k1(t0+2) P6:B_k1(t0+2) P7:A_k0(t1+2) P8:B_k0(t1+2).
// z=0: Q=(x@Wq^T+bq)*0.125*log2e -> [b,h,s,hd]; z=1: K; z=2: V^T -> [b,h,hd,s].
#define QSTG(DBUF, UNIT, SRCP, TOFF)                                                      \
  { _Pragma("unroll") for (int i_ = 0; i_ < 2; ++i_)                                      \
      __builtin_amdgcn_global_load_lds(                                                   \
          (const __attribute__((address_space(1))) void*)(SRCP[i_] + (TOFF)),             \
          (__attribute__((address_space(3))) void*)(L[DBUF][UNIT] + (i_ * 512 + w * 64) * 16), \
          16, 0, 0); }

#define QPH(CBUF, KS, NH, STG)                                                            \
  {                                                                                       \
    bf16x8 af[8], bfr[2];                                                                 \
    _Pragma("unroll") for (int mf = 0; mf < 8; ++mf)                                      \
      af[mf] = *reinterpret_cast<const bf16x8*>(L[CBUF][KS] + (arow + mf * 16) * 64 + ckoff); \
    _Pragma("unroll") for (int nf = 0; nf < 2; ++nf)                                      \
      bfr[nf] = *reinterpret_cast<const bf16x8*>(                                         \
          L[CBUF][2 + KS] + (brow + (NH * 2 + nf) * 16) * 64 + ckoff);                    \
    STG;                                                                                  \
    __builtin_amdgcn_sched_barrier(0);                                                    \
    __builtin_amdgcn_s_barrier();                                                         \
    __builtin_amdgcn_s_setprio(1);                                                        \
    _Pragma("unroll") for (int mf = 0; mf < 8; ++mf)                                      \
      _Pragma("unroll") for (int nf = 0; nf < 2; ++nf)                                    \
        acc[mf][NH * 2 + nf] = __builtin_amdgcn_mfma_f32_16x16x32_bf16(                   \
            af[mf], bfr[nf], acc[mf][NH * 2 + nf], 0, 0, 0);                              \
    __builtin_amdgcn_s_setprio(0);                                                        \
    __builtin_amdgcn_s_barrier();                                                         \
  }

__global__ __launch_bounds__(512, 2) void gemm_qkv8(const bf16* __restrict__ x,
                                                    const bf16* __restrict__ wq,
                                                    const bf16* __restrict__ wk,
                                                    const bf16* __restrict__ wv,
                                                    const float* __restrict__ bq,
                                                    const float* __restrict__ bk,
                                                    const float* __restrict__ bv,
                                                    bf16* __restrict__ Qo, bf16* __restrict__ Ko,
                                                    bf16* __restrict__ Vto) {
  const int tid = threadIdx.x;
  const int lane = tid & 63;
  const int w = tid >> 6;             // 0..7
  const int wm = w >> 2, wn = w & 3;  // 2M x 4N wave grid
  const int l15 = lane & 15, g = lane >> 4;
  const int z = blockIdx.z;

  const bf16* A; const bf16* Bm; int bm, bn;
  if (z < 2) { A = x; Bm = z ? wk : wq; bm = blockIdx.y; bn = blockIdx.x; }
  else       { A = wv; Bm = x;          bm = blockIdx.x; bn = blockIdx.y; }

  __shared__ __align__(16) unsigned char L[2][4][16384];  // [buf][A_k0,A_k1,B_k0,B_k1]

  // staging sources: unit = 1024 chunks of 16B (256 rows x 4); source chunk pre-swizzled
  const bf16* srcA[2];
  const bf16* srcB[2];
#pragma unroll
  for (int i = 0; i < 2; ++i) {
    int ch = i * 512 + tid;
    int r = ch >> 2, cl = ch & 3;
    int cs = cl ^ (r & 3) ^ ((r >> 2) & 3);
    srcA[i] = A  + (size_t)(bm * 256 + r) * Kk + cs * 8;
    srcB[i] = Bm + (size_t)(bn * 256 + r) * Kk + cs * 8;
  }
  const int ckoff = ((g ^ (l15 & 3) ^ (l15 >> 2)) << 4);  // swizzled chunk byte offset
  const int arow = wm * 128 + l15;
  const int brow = wn * 64 + l15;

  f32x4 acc[8][4] = {};

  // prologue: t0=0 fully + A_k0/B_k0 of t1=1; retire first 2 units
  QSTG(0, 0, srcA, 0);
  QSTG(0, 2, srcB, 0);
  QSTG(0, 1, srcA, 32);
  QSTG(0, 3, srcB, 32);
  QSTG(1, 0, srcA, 64);
  QSTG(1, 2, srcB, 64);
  __builtin_amdgcn_sched_barrier(0);
  WAITV(8);
  __builtin_amdgcn_s_barrier();

  for (int j = 0; j < 8; ++j) {
    const int t1o = (2 * j + 1) * 64, tn0 = (2 * j + 2) * 64, tn1 = (2 * j + 3) * 64;
    const bool pf = (j < 7);
    QPH(0, 0, 0, { QSTG(1, 1, srcA, t1o + 32); });
    QPH(0, 0, 1, { QSTG(1, 3, srcB, t1o + 32); WAITV(8); });
    QPH(0, 1, 0, { if (pf) QSTG(0, 0, srcA, tn0); });
    QPH(0, 1, 1, { if (pf) { QSTG(0, 2, srcB, tn0); WAITV(8); } else { WAITV(0); } });
    QPH(1, 0, 0, { if (pf) QSTG(0, 1, srcA, tn0 + 32); });
    QPH(1, 0, 1, { if (pf) { QSTG(0, 3, srcB, tn0 + 32); WAITV(8); } else { WAITV(0); } });
    QPH(1, 1, 0, { if (pf) QSTG(1, 0, srcA, tn1); });
    QPH(1, 1, 1, { if (pf) { QSTG(1, 2, srcB, tn1); WAITV(8); } });
  }

  // epilogue: D layout col(l15)=n, row(g*4+rr)=m within 16x16 fragment
  if (z < 2) {
    const float* bias = z ? bk : bq;
    bf16* out = z ? Ko : Qo;
    const float scale = z ? 1.f : 0.125f * 1.44269504088896340736f;
#pragma unroll
    for (int nf = 0; nf < 4; ++nf) {
      int n = bn * 256 + wn * 64 + nf * 16 + l15;
      float bv_ = bias[n];
      int h = n >> 6, hd = n & 63;
#pragma unroll
      for (int mf = 0; mf < 8; ++mf)
#pragma unroll
        for (int rr = 0; rr < 4; ++rr) {
          int m = bm * 256 + wm * 128 + mf * 16 + g * 4 + rr;
          float val = (acc[mf][nf][rr] + bv_) * scale;
          size_t adr = ((size_t)((m >> 10) * Hh + h) * Ss + (m & 1023)) * HDd + hd;
          out[adr] = (bf16)val;
        }
    }
  } else {  // V^T: m = d-index, n = bs-index, bias per m
#pragma unroll
    for (int mf = 0; mf < 8; ++mf)
#pragma unroll
      for (int rr = 0; rr < 4; ++rr) {
        int m = bm * 256 + wm * 128 + mf * 16 + g * 4 + rr;
        float bv_ = bv[m];
#pragma unroll
        for (int nf = 0; nf < 4; ++nf) {
          int n = bn * 256 + wn * 64 + nf * 16 + l15;
          size_t adr = ((size_t)((n >> 10) * Hh + (m >> 6)) * HDd + (m & 63)) * Ss + (n & 1023);
          Vto[adr] = (bf16)(acc[mf][nf][rr] + bv_);
        }
      }
  }
}

// ---------------- final projection (1D grid, XCD-clustered): out = ctx @ Wf^T + bf ----------------
__global__ __launch_bounds__(256) void gemm_out(const bf16* __restrict__ A, const bf16* __restrict__ Bm,
                                                const float* __restrict__ bias, float* __restrict__ out) {
  const int tid = threadIdx.x;
  const int lane = tid & 63;
  const int w = tid >> 6;
  const int l15 = lane & 15, g = lane >> 4;
  const int id = blockIdx.x;                    // 512 blocks
  const int xcd = id & 7, slot = id >> 3;       // 64 slots per XCD
  const int bm = xcd * 8 + (slot >> 3);         // 8 bn-blocks of one ctx-panel per XCD
  const int bn = slot & 7;
  __shared__ __align__(16) unsigned char As[128 * 128];
  __shared__ __align__(16) unsigned char Bs[128 * 128];
  f32x4 acc[4][4] = {};
  gemm_loop(A, Bm, bm, bn, As, Bs, w, lane, l15, g, acc);
  const int wr = (w >> 1) * 64, wc = (w & 1) * 64;
#pragma unroll
  for (int ni = 0; ni < 4; ++ni) {
    int col = bn * 128 + wc + ni * 16 + l15;
    float bv_ = bias[col];
#pragma unroll
    for (int mi = 0; mi < 4; ++mi)
#pragma unroll
      for (int r = 0; r < 4; ++r) {
        int row = bm * 128 + wr + mi * 16 + g * 4 + r;
        out[(size_t)row * Dd + col] = acc[mi][ni][r] + bv_;
      }
  }
}

// ---------------- fused attention (exact R6 structure + exp2; verified best) ----------------
__global__ __launch_bounds__(512, 4) void attn_fused(const bf16* __restrict__ Q,
                                                     const bf16* __restrict__ Kt,
                                                     const bf16* __restrict__ Vt,
                                                     float* __restrict__ probs,
                                                     bf16* __restrict__ ctx) {
  const int tid = threadIdx.x;
  const int lane = tid & 63;
  const int w = tid >> 6;
  const int l15 = lane & 15, g = lane >> 4;
  const int bid = blockIdx.x;
  const int bh = (bid & 7) * 16 + ((bid >> 3) & 15);  // same head -> same bid%8 -> same XCD
  const int qt = bid >> 7;
  const int q0 = qt * 128 + w * 16;

  __shared__ __align__(16) unsigned char KV[4][16384];  // p1: K rotation; p2: K slabs 0/1, V 2/3
  __shared__ __align__(16) bf16 Ps[8][16][40];          // per-wave P chunk (32 k + pad)

  bf16x8 qf0, qf1;
  {
    const bf16* qp = Q + ((size_t)bh * Ss + q0 + l15) * HDd + g * 8;
    qf0 = *reinterpret_cast<const bf16x8*>(qp);
    qf1 = *reinterpret_cast<const bf16x8*>(qp + 32);
  }
  const bf16* kbase = Kt + (size_t)bh * Ss * HDd;
  const bf16* vbase = Vt + (size_t)bh * HDd * Ss;

  const bf16* ksrc[2];
  const bf16* vsrc[2];
#pragma unroll
  for (int i = 0; i < 2; ++i) {
    int ch = i * 512 + tid;
    int kr = ch >> 3, kc = (ch & 7) ^ (kr & 7);
    ksrc[i] = kbase + (size_t)kr * HDd + kc * 8;
    int vr = ch >> 4, vc = (ch & 15) ^ (vr & 15);
    vsrc[i] = vbase + (size_t)vr * Ss + vc * 8;
  }

#define SK(slab, t)                                                                       \
  {                                                                                       \
    _Pragma("unroll") for (int i = 0; i < 2; ++i)                                         \
        __builtin_amdgcn_global_load_lds(                                                 \
            (const __attribute__((address_space(1))) void*)(ksrc[i] + (size_t)(t) * 128 * HDd), \
            (__attribute__((address_space(3))) void*)(KV[slab] + (i * 512 + w * 64) * 16),\
            16, 0, 0);                                                                    \
  }
#define SV(slab, t)                                                                       \
  {                                                                                       \
    _Pragma("unroll") for (int i = 0; i < 2; ++i)                                         \
        __builtin_amdgcn_global_load_lds(                                                 \
            (const __attribute__((address_space(1))) void*)(vsrc[i] + (t) * 128),         \
            (__attribute__((address_space(3))) void*)(KV[slab] + (i * 512 + w * 64) * 16),\
            16, 0, 0);                                                                    \
  }

  auto kread = [&](int slab, int nk, int half) -> bf16x8 {
    int row = nk * 16 + l15;
    int chunk = (half * 4 + g) ^ (l15 & 7);
    return *reinterpret_cast<const bf16x8*>(KV[slab] + row * 128 + chunk * 16);
  };
  auto vread = [&](int slab, int nkp, int ni) -> bf16x8 {
    int row = ni * 16 + l15;
    int chunk = (nkp * 4 + g) ^ l15;
    return *reinterpret_cast<const bf16x8*>(KV[slab] + row * 256 + chunk * 16);
  };

  // ---- pass 1: row sum of exp2(score) ----
  float lr0 = 0.f, lr1 = 0.f, lr2 = 0.f, lr3 = 0.f;
  SK(0, 0); SK(1, 1); SK(2, 2);
  __builtin_amdgcn_sched_barrier(0);
  WAITV(4);
  PHASE_BAR;
  for (int kt = 0; kt < 8; ++kt) {
    if (kt <= 4)      { SK((kt + 3) & 3, kt + 3); }
    else if (kt == 7) { SK(0, 0); SV(2, 0); }
    __builtin_amdgcn_sched_barrier(0);
    const int ks = kt & 3;
#pragma unroll
    for (int nk = 0; nk < 8; ++nk) {
      f32x4 sc = {0.f, 0.f, 0.f, 0.f};
      bf16x8 k0 = kread(ks, nk, 0), k1 = kread(ks, nk, 1);
      __builtin_amdgcn_s_setprio(1);
      sc = __builtin_amdgcn_mfma_f32_16x16x32_bf16(k0, qf0, sc, 0, 0, 0);
      sc = __builtin_amdgcn_mfma_f32_16x16x32_bf16(k1, qf1, sc, 0, 0, 0);
      __builtin_amdgcn_s_setprio(0);
      lr0 += __builtin_amdgcn_exp2f(sc[0]);
      lr1 += __builtin_amdgcn_exp2f(sc[1]);
      lr2 += __builtin_amdgcn_exp2f(sc[2]);
      lr3 += __builtin_amdgcn_exp2f(sc[3]);
    }
    if (kt <= 4)      { WAITV(4); }
    else if (kt == 5) { WAITV(2); }
    else              { WAITV(0); }
    PHASE_BAR;
  }
  float lsum = (lr0 + lr1) + (lr2 + lr3);
  lsum += __shfl_xor(lsum, 16, 64);
  lsum += __shfl_xor(lsum, 32, 64);
  const float rl = 1.f / lsum;

  float* const prow = probs + ((size_t)bh * Ss + q0 + l15) * Ss;
  f32x4 cacc[4] = {};

  // ---- pass 2 (ascending; K[kt] slab kt&1, V[kt] slab 2+(kt&1)) ----
  for (int kt = 0; kt < 8; ++kt) {
    if (kt < 7) { SK((kt + 1) & 1, kt + 1); SV(2 + ((kt + 1) & 1), kt + 1); }
    __builtin_amdgcn_sched_barrier(0);
    const int ks = kt & 1, vs = 2 + (kt & 1);
#pragma unroll
    for (int nkp = 0; nkp < 4; ++nkp) {
#pragma unroll
      for (int h = 0; h < 2; ++h) {
        int nk = nkp * 2 + h;
        f32x4 sc = {0.f, 0.f, 0.f, 0.f};
        bf16x8 k0 = kread(ks, nk, 0), k1 = kread(ks, nk, 1);
        __builtin_amdgcn_s_setprio(1);
        sc = __builtin_amdgcn_mfma_f32_16x16x32_bf16(k0, qf0, sc, 0, 0, 0);
        sc = __builtin_amdgcn_mfma_f32_16x16x32_bf16(k1, qf1, sc, 0, 0, 0);
        __builtin_amdgcn_s_setprio(0);
        f32x4 pv;
#pragma unroll
        for (int r = 0; r < 4; ++r) pv[r] = __builtin_amdgcn_exp2f(sc[r]) * rl;
        *reinterpret_cast<f32x4*>(prow + kt * 128 + nk * 16 + g * 4) = pv;
        bf16x4 pb = { (bf16)pv[0], (bf16)pv[1], (bf16)pv[2], (bf16)pv[3] };
        *reinterpret_cast<bf16x4*>(&Ps[w][l15][h * 16 + g * 4]) = pb;
      }
      bf16x8 pf = *reinterpret_cast<const bf16x8*>(&Ps[w][l15][g * 8]);
      bf16x8 vf0 = vread(vs, nkp, 0), vf1 = vread(vs, nkp, 1);
      bf16x8 vf2 = vread(vs, nkp, 2), vf3 = vread(vs, nkp, 3);
      __builtin_amdgcn_s_setprio(1);
      cacc[0] = __builtin_amdgcn_mfma_f32_16x16x32_bf16(pf, vf0, cacc[0], 0, 0, 0);
      cacc[1] = __builtin_amdgcn_mfma_f32_16x16x32_bf16(pf, vf1, cacc[1], 0, 0, 0);
      cacc[2] = __builtin_amdgcn_mfma_f32_16x16x32_bf16(pf, vf2, cacc[2], 0, 0, 0);
      cacc[3] = __builtin_amdgcn_mfma_f32_16x16x32_bf16(pf, vf3, cacc[3], 0, 0, 0);
      __builtin_amdgcn_s_setprio(0);
    }
    if (kt < 7) {
      WAITV(8);
      PHASE_BAR;
    }
  }
#undef SK
#undef SV

  const int bb = bh >> 4, hh = bh & 15;
#pragma unroll
  for (int ni = 0; ni < 4; ++ni)
#pragma unroll
    for (int r = 0; r < 4; ++r) {
      int q = q0 + g * 4 + r;
      ctx[((size_t)bb * Ss + q) * Dd + hh * 64 + ni * 16 + l15] = (bf16)cacc[ni][r];
    }
}

// ---------------- launch ----------------
extern "C" void kernel_launch(void* const* d_in, const int* in_sizes, int n_in,
                              void* d_out, int out_size, void* d_ws, size_t ws_size,
                              hipStream_t stream) {
  (void)in_sizes; (void)n_in; (void)out_size; (void)ws_size;
  const float* x   = (const float*)d_in[0];
  const float* Wq  = (const float*)d_in[1];
  const float* bq  = (const float*)d_in[2];
  const float* Wk  = (const float*)d_in[3];
  const float* bk  = (const float*)d_in[4];
  const float* Wv  = (const float*)d_in[5];
  const float* bv  = (const float*)d_in[6];
  const float* Wf  = (const float*)d_in[7];
  const float* bfp = (const float*)d_in[8];

  char* ws = (char*)d_ws;
  size_t off = 0;
  auto alloc = [&](size_t n) { void* p = ws + off; off += (n + 255) & ~(size_t)255; return p; };
  bf16* xb   = (bf16*)alloc((size_t)Mm * Dd * 2);
  bf16* wqb  = (bf16*)alloc((size_t)Dd * Dd * 2);
  bf16* wkb  = (bf16*)alloc((size_t)Dd * Dd * 2);
  bf16* wvb  = (bf16*)alloc((size_t)Dd * Dd * 2);
  bf16* wfb  = (bf16*)alloc((size_t)Dd * Dd * 2);
  bf16* Qb   = (bf16*)alloc((size_t)Mm * Dd * 2);
  bf16* Kb   = (bf16*)alloc((size_t)Mm * Dd * 2);
  bf16* Vtb  = (bf16*)alloc((size_t)Mm * Dd * 2);
  bf16* ctxb = (bf16*)alloc((size_t)Mm * Dd * 2);

  CastArgs ca;
  ca.src[0] = x;  ca.dst[0] = xb;  int n0 = Mm * Dd / 4;
  ca.src[1] = Wq; ca.dst[1] = wqb; int nw = Dd * Dd / 4;
  ca.src[2] = Wk; ca.dst[2] = wkb;
  ca.src[3] = Wv; ca.dst[3] = wvb;
  ca.src[4] = Wf; ca.dst[4] = wfb;
  ca.cum[0] = n0; ca.cum[1] = n0 + nw; ca.cum[2] = n0 + 2 * nw;
  ca.cum[3] = n0 + 3 * nw; ca.cum[4] = n0 + 4 * nw;
  int tot = ca.cum[4];
  cast_all<<<(tot + 255) / 256, 256, 0, stream>>>(ca, tot);

  gemm_qkv8<<<dim3(Dd / 256, Mm / 256, 3), 512, 0, stream>>>(xb, wqb, wkb, wvb, bq, bk, bv,
                                                             Qb, Kb, Vtb);

  float* probs = (float*)d_out + (size_t)Mm * Dd;
  attn_fused<<<dim3(Bb * Hh * 8), 512, 0, stream>>>(Qb, Kb, Vtb, probs, ctxb);

  gemm_out<<<dim3(64 * 8), 256, 0, stream>>>(ctxb, wfb, bfp, (float*)d_out);
}

// Round 12
// 279.161 us; speedup vs baseline: 1.0334x; 1.0334x over previous
//
#include <hip/hip_runtime.h>

typedef __bf16 bf16;
typedef __bf16 bf16x4 __attribute__((ext_vector_type(4)));
typedef __bf16 bf16x8 __attribute__((ext_vector_type(8)));
typedef float  f32x4  __attribute__((ext_vector_type(4)));

constexpr int Bb = 8, Ss = 1024, Dd = 1024, Hh = 16, HDd = 64;
constexpr int Mm = Bb * Ss;   // 8192
constexpr int Kk = 1024;

#define WAITV(n) asm volatile("s_waitcnt vmcnt(" #n ")" ::: "memory")
#define PHASE_BAR { __builtin_amdgcn_s_barrier(); __builtin_amdgcn_sched_barrier(0); }

// ---------------- fused cast f32 -> bf16 (5 segments, float4 chunks) ----------------
struct CastArgs {
  const float* src[5];
  bf16* dst[5];
  int cum[5];
};
__global__ void cast_all(CastArgs a, int tot) {
  int i = blockIdx.x * blockDim.x + threadIdx.x;
  if (i >= tot) return;
  int s, base;
  if (i < a.cum[0])      { s = 0; base = 0; }
  else if (i < a.cum[1]) { s = 1; base = a.cum[0]; }
  else if (i < a.cum[2]) { s = 2; base = a.cum[1]; }
  else if (i < a.cum[3]) { s = 3; base = a.cum[2]; }
  else                   { s = 4; base = a.cum[3]; }
  int j = i - base;
  float4 v = reinterpret_cast<const float4*>(a.src[s])[j];
  bf16x4 o = { (bf16)v.x, (bf16)v.y, (bf16)v.z, (bf16)v.w };
  reinterpret_cast<bf16x4*>(a.dst[s])[j] = o;
}

// ---------------- 128x128 2-barrier GEMM core (verified) ----------------
__device__ __forceinline__ void gemm_loop(const bf16* __restrict__ A, const bf16* __restrict__ Bm,
                                          int bm, int bn, unsigned char* As, unsigned char* Bs,
                                          int w, int lane, int l15, int g, f32x4 (&acc)[4][4]) {
  const bf16* srcA[4];
  const bf16* srcB[4];
#pragma unroll
  for (int i = 0; i < 4; ++i) {
    int gch = (w * 4 + i) * 64 + lane;  // chunk id 0..1023
    int r = gch >> 3, c = gch & 7, cs = c ^ (r & 7);
    srcA[i] = A  + (size_t)(bm * 128 + r) * Kk + cs * 8;
    srcB[i] = Bm + (size_t)(bn * 128 + r) * Kk + cs * 8;
  }
  for (int kt = 0; kt < Kk / 64; ++kt) {
    __syncthreads();
#pragma unroll
    for (int i = 0; i < 4; ++i) {
      __builtin_amdgcn_global_load_lds(
          (const __attribute__((address_space(1))) void*)(srcA[i] + kt * 64),
          (__attribute__((address_space(3))) void*)(As + (w * 4 + i) * 1024), 16, 0, 0);
      __builtin_amdgcn_global_load_lds(
          (const __attribute__((address_space(1))) void*)(srcB[i] + kt * 64),
          (__attribute__((address_space(3))) void*)(Bs + (w * 4 + i) * 1024), 16, 0, 0);
    }
    __syncthreads();
#pragma unroll
    for (int kk = 0; kk < 2; ++kk) {
      const int kb = kk * 64 + g * 16;
      bf16x8 af[4], bfr[4];
#pragma unroll
      for (int mi = 0; mi < 4; ++mi) {
        int row = ((w >> 1) * 64) + mi * 16 + l15;
        af[mi] = *reinterpret_cast<const bf16x8*>(As + row * 128 + (kb ^ ((row & 7) << 4)));
      }
#pragma unroll
      for (int ni = 0; ni < 4; ++ni) {
        int row = ((w & 1) * 64) + ni * 16 + l15;
        bfr[ni] = *reinterpret_cast<const bf16x8*>(Bs + row * 128 + (kb ^ ((row & 7) << 4)));
      }
#pragma unroll
      for (int mi = 0; mi < 4; ++mi)
#pragma unroll
        for (int ni = 0; ni < 4; ++ni)
          acc[mi][ni] = __builtin_amdgcn_mfma_f32_16x16x32_bf16(af[mi], bfr[ni], acc[mi][ni], 0, 0, 0);
    }
  }
}

// ---------------- fused QKV projection (1D grid, XCD-clustered; verified R10) ----------------
// All 24 (bn,z) blocks sharing one bm's A-panel run consecutively on ONE XCD.
// z=0: Q = (x@Wq^T + bq)*(0.125*log2e) -> [b,h,s,hd]; z=1: K; z=2: V^T -> [b,h,hd,s]
__global__ __launch_bounds__(256) void gemm_qkv(const bf16* __restrict__ x,
                                                const bf16* __restrict__ wq, const bf16* __restrict__ wk,
                                                const bf16* __restrict__ wv,
                                                const float* __restrict__ bq, const float* __restrict__ bk,
                                                const float* __restrict__ bv,
                                                bf16* __restrict__ Qo, bf16* __restrict__ Ko,
                                                bf16* __restrict__ Vto) {
  const int tid = threadIdx.x;
  const int lane = tid & 63;
  const int w = tid >> 6;
  const int l15 = lane & 15, g = lane >> 4;

  const int id = blockIdx.x;
  const int xcd = id & 7, slot = id >> 3;       // 192 slots per XCD
  const int bmg = slot / 24, rem = slot % 24;   // 8 bm-groups x 24 (bn,z)
  const int bmx = xcd * 8 + bmg;
  const int bnx = rem & 7;
  const int z = rem >> 3;

  const bf16* A; const bf16* Bm; int bm, bn;
  if (z < 2) { A = x; Bm = z ? wk : wq; bm = bmx; bn = bnx; }
  else       { A = wv; Bm = x;          bm = bnx; bn = bmx; }

  __shared__ __align__(16) unsigned char As[128 * 128];
  __shared__ __align__(16) unsigned char Bs[128 * 128];
  f32x4 acc[4][4] = {};
  gemm_loop(A, Bm, bm, bn, As, Bs, w, lane, l15, g, acc);

  const int wr = (w >> 1) * 64, wc = (w & 1) * 64;
  if (z < 2) {
    const float* bias = z ? bk : bq;
    bf16* out = z ? Ko : Qo;
    const float scale = z ? 1.f : 0.125f * 1.44269504088896340736f;
#pragma unroll
    for (int ni = 0; ni < 4; ++ni) {
      int col = bn * 128 + wc + ni * 16 + l15;
      float bv_ = bias[col];
#pragma unroll
      for (int mi = 0; mi < 4; ++mi)
#pragma unroll
        for (int r = 0; r < 4; ++r) {
          int row = bm * 128 + wr + mi * 16 + g * 4 + r;
          float val = (acc[mi][ni][r] + bv_) * scale;
          size_t adr = ((size_t)((row >> 10) * Hh + (col >> 6)) * Ss + (row & 1023)) * HDd + (col & 63);
          out[adr] = (bf16)val;
        }
    }
  } else {  // V^T: row = d-index, col = bs-index, bias per row
#pragma unroll
    for (int mi = 0; mi < 4; ++mi)
#pragma unroll
      for (int r = 0; r < 4; ++r) {
        int row = bm * 128 + wr + mi * 16 + g * 4 + r;
        float bv_ = bv[row];
#pragma unroll
        for (int ni = 0; ni < 4; ++ni) {
          int col = bn * 128 + wc + ni * 16 + l15;
          size_t adr = ((size_t)((col >> 10) * Hh + (row >> 6)) * HDd + (row & 63)) * Ss + (col & 1023);
          Vto[adr] = (bf16)(acc[mi][ni][r] + bv_);
        }
      }
  }
}

// ---------------- final projection (1D grid, XCD-clustered): out = ctx @ Wf^T + bf ----------------
__global__ __launch_bounds__(256) void gemm_out(const bf16* __restrict__ A, const bf16* __restrict__ Bm,
                                                const float* __restrict__ bias, float* __restrict__ out) {
  const int tid = threadIdx.x;
  const int lane = tid & 63;
  const int w = tid >> 6;
  const int l15 = lane & 15, g = lane >> 4;
  const int id = blockIdx.x;                    // 512 blocks
  const int xcd = id & 7, slot = id >> 3;       // 64 slots per XCD
  const int bm = xcd * 8 + (slot >> 3);
  const int bn = slot & 7;
  __shared__ __align__(16) unsigned char As[128 * 128];
  __shared__ __align__(16) unsigned char Bs[128 * 128];
  f32x4 acc[4][4] = {};
  gemm_loop(A, Bm, bm, bn, As, Bs, w, lane, l15, g, acc);
  const int wr = (w >> 1) * 64, wc = (w & 1) * 64;
#pragma unroll
  for (int ni = 0; ni < 4; ++ni) {
    int col = bn * 128 + wc + ni * 16 + l15;
    float bv_ = bias[col];
#pragma unroll
    for (int mi = 0; mi < 4; ++mi)
#pragma unroll
      for (int r = 0; r < 4; ++r) {
        int row = bm * 128 + wr + mi * 16 + g * 4 + r;
        out[(size_t)row * Dd + col] = acc[mi][ni][r] + bv_;
      }
  }
}

// ---------------- fused attention (R6 schedule + exp2; NEW head-clustered XCD decode) ----------------
// Decode change only: per XCD, the 8 q-tiles of one head run CONSECUTIVELY
// (bh = xcd*16 + (slot>>3), qt = slot&7). Resident set per XCD = 8 heads x 256 KB = 2 MB
// (< 4 MB L2, 2x slack) vs old decode's 16 heads x 256 KB = 4 MB (= exactly L2 -> thrash).
__global__ __launch_bounds__(512, 4) void attn_fused(const bf16* __restrict__ Q,
                                                     const bf16* __restrict__ Kt,
                                                     const bf16* __restrict__ Vt,
                                                     float* __restrict__ probs,
                                                     bf16* __restrict__ ctx) {
  const int tid = threadIdx.x;
  const int lane = tid & 63;
  const int w = tid >> 6;
  const int l15 = lane & 15, g = lane >> 4;
  const int bid = blockIdx.x;
  const int slot = bid >> 3;
  const int bh = (bid & 7) * 16 + (slot >> 3);  // head pinned to XCD, q-tiles consecutive
  const int qt = slot & 7;
  const int q0 = qt * 128 + w * 16;

  __shared__ __align__(16) unsigned char KV[4][16384];  // p1: K rotation; p2: K slabs 0/1, V 2/3
  __shared__ __align__(16) bf16 Ps[8][16][40];          // per-wave P chunk (32 k + pad)

  bf16x8 qf0, qf1;
  {
    const bf16* qp = Q + ((size_t)bh * Ss + q0 + l15) * HDd + g * 8;
    qf0 = *reinterpret_cast<const bf16x8*>(qp);
    qf1 = *reinterpret_cast<const bf16x8*>(qp + 32);
  }
  const bf16* kbase = Kt + (size_t)bh * Ss * HDd;
  const bf16* vbase = Vt + (size_t)bh * HDd * Ss;

  const bf16* ksrc[2];
  const bf16* vsrc[2];
#pragma unroll
  for (int i = 0; i < 2; ++i) {
    int ch = i * 512 + tid;
    int kr = ch >> 3, kc = (ch & 7) ^ (kr & 7);
    ksrc[i] = kbase + (size_t)kr * HDd + kc * 8;
    int vr = ch >> 4, vc = (ch & 15) ^ (vr & 15);
    vsrc[i] = vbase + (size_t)vr * Ss + vc * 8;
  }

#define SK(slab, t)                                                                       \
  {                                                                                       \
    _Pragma("unroll") for (int i = 0; i < 2; ++i)                                         \
        __builtin_amdgcn_global_load_lds(                                                 \
            (const __attribute__((address_space(1))) void*)(ksrc[i] + (size_t)(t) * 128 * HDd), \
            (__attribute__((address_space(3))) void*)(KV[slab] + (i * 512 + w * 64) * 16),\
            16, 0, 0);                                                                    \
  }
#define SV(slab, t)                                                                       \
  {                                                                                       \
    _Pragma("unroll") for (int i = 0; i < 2; ++i)                                         \
        __builtin_amdgcn_global_load_lds(                                                 \
            (const __attribute__((address_space(1))) void*)(vsrc[i] + (t) * 128),         \
            (__attribute__((address_space(3))) void*)(KV[slab] + (i * 512 + w * 64) * 16),\
            16, 0, 0);                                                                    \
  }

  auto kread = [&](int slab, int nk, int half) -> bf16x8 {
    int row = nk * 16 + l15;
    int chunk = (half * 4 + g) ^ (l15 & 7);
    return *reinterpret_cast<const bf16x8*>(KV[slab] + row * 128 + chunk * 16);
  };
  auto vread = [&](int slab, int nkp, int ni) -> bf16x8 {
    int row = ni * 16 + l15;
    int chunk = (nkp * 4 + g) ^ l15;
    return *reinterpret_cast<const bf16x8*>(KV[slab] + row * 256 + chunk * 16);
  };

  // ---- pass 1: row sum of exp2(score) ----
  float lr0 = 0.f, lr1 = 0.f, lr2 = 0.f, lr3 = 0.f;
  SK(0, 0); SK(1, 1); SK(2, 2);
  __builtin_amdgcn_sched_barrier(0);
  WAITV(4);
  PHASE_BAR;
  for (int kt = 0; kt < 8; ++kt) {
    if (kt <= 4)      { SK((kt + 3) & 3, kt + 3); }
    else if (kt == 7) { SK(0, 0); SV(2, 0); }
    __builtin_amdgcn_sched_barrier(0);
    const int ks = kt & 3;
#pragma unroll
    for (int nk = 0; nk < 8; ++nk) {
      f32x4 sc = {0.f, 0.f, 0.f, 0.f};
      bf16x8 k0 = kread(ks, nk, 0), k1 = kread(ks, nk, 1);
      __builtin_amdgcn_s_setprio(1);
      sc = __builtin_amdgcn_mfma_f32_16x16x32_bf16(k0, qf0, sc, 0, 0, 0);
      sc = __builtin_amdgcn_mfma_f32_16x16x32_bf16(k1, qf1, sc, 0, 0, 0);
      __builtin_amdgcn_s_setprio(0);
      lr0 += __builtin_amdgcn_exp2f(sc[0]);
      lr1 += __builtin_amdgcn_exp2f(sc[1]);
      lr2 += __builtin_amdgcn_exp2f(sc[2]);
      lr3 += __builtin_amdgcn_exp2f(sc[3]);
    }
    if (kt <= 4)      { WAITV(4); }
    else if (kt == 5) { WAITV(2); }
    else              { WAITV(0); }
    PHASE_BAR;
  }
  float lsum = (lr0 + lr1) + (lr2 + lr3);
  lsum += __shfl_xor(lsum, 16, 64);
  lsum += __shfl_xor(lsum, 32, 64);
  const float rl = 1.f / lsum;

  float* const prow = probs + ((size_t)bh * Ss + q0 + l15) * Ss;
  f32x4 cacc[4] = {};

  // ---- pass 2 (ascending; K[kt] slab kt&1, V[kt] slab 2+(kt&1)) ----
  for (int kt = 0; kt < 8; ++kt) {
    if (kt < 7) { SK((kt + 1) & 1, kt + 1); SV(2 + ((kt + 1) & 1), kt + 1); }
    __builtin_amdgcn_sched_barrier(0);
    const int ks = kt & 1, vs = 2 + (kt & 1);
#pragma unroll
    for (int nkp = 0; nkp < 4; ++nkp) {
#pragma unroll
      for (int h = 0; h < 2; ++h) {
        int nk = nkp * 2 + h;
        f32x4 sc = {0.f, 0.f, 0.f, 0.f};
        bf16x8 k0 = kread(ks, nk, 0), k1 = kread(ks, nk, 1);
        __builtin_amdgcn_s_setprio(1);
        sc = __builtin_amdgcn_mfma_f32_16x16x32_bf16(k0, qf0, sc, 0, 0, 0);
        sc = __builtin_amdgcn_mfma_f32_16x16x32_bf16(k1, qf1, sc, 0, 0, 0);
        __builtin_amdgcn_s_setprio(0);
        f32x4 pv;
#pragma unroll
        for (int r = 0; r < 4; ++r) pv[r] = __builtin_amdgcn_exp2f(sc[r]) * rl;
        *reinterpret_cast<f32x4*>(prow + kt * 128 + nk * 16 + g * 4) = pv;
        bf16x4 pb = { (bf16)pv[0], (bf16)pv[1], (bf16)pv[2], (bf16)pv[3] };
        *reinterpret_cast<bf16x4*>(&Ps[w][l15][h * 16 + g * 4]) = pb;
      }
      bf16x8 pf = *reinterpret_cast<const bf16x8*>(&Ps[w][l15][g * 8]);
      bf16x8 vf0 = vread(vs, nkp, 0), vf1 = vread(vs, nkp, 1);
      bf16x8 vf2 = vread(vs, nkp, 2), vf3 = vread(vs, nkp, 3);
      __builtin_amdgcn_s_setprio(1);
      cacc[0] = __builtin_amdgcn_mfma_f32_16x16x32_bf16(pf, vf0, cacc[0], 0, 0, 0);
      cacc[1] = __builtin_amdgcn_mfma_f32_16x16x32_bf16(pf, vf1, cacc[1], 0, 0, 0);
      cacc[2] = __builtin_amdgcn_mfma_f32_16x16x32_bf16(pf, vf2, cacc[2], 0, 0, 0);
      cacc[3] = __builtin_amdgcn_mfma_f32_16x16x32_bf16(pf, vf3, cacc[3], 0, 0, 0);
      __builtin_amdgcn_s_setprio(0);
    }
    if (kt < 7) {
      WAITV(8);
      PHASE_BAR;
    }
  }
#undef SK
#undef SV

  const int bb = bh >> 4, hh = bh & 15;
#pragma unroll
  for (int ni = 0; ni < 4; ++ni)
#pragma unroll
    for (int r = 0; r < 4; ++r) {
      int q = q0 + g * 4 + r;
      ctx[((size_t)bb * Ss + q) * Dd + hh * 64 + ni * 16 + l15] = (bf16)cacc[ni][r];
    }
}

// ---------------- launch ----------------
extern "C" void kernel_launch(void* const* d_in, const int* in_sizes, int n_in,
                              void* d_out, int out_size, void* d_ws, size_t ws_size,
                              hipStream_t stream) {
  (void)in_sizes; (void)n_in; (void)out_size; (void)ws_size;
  const float* x   = (const float*)d_in[0];
  const float* Wq  = (const float*)d_in[1];
  const float* bq  = (const float*)d_in[2];
  const float* Wk  = (const float*)d_in[3];
  const float* bk  = (const float*)d_in[4];
  const float* Wv  = (const float*)d_in[5];
  const float* bv  = (const float*)d_in[6];
  const float* Wf  = (const float*)d_in[7];
  const float* bfp = (const float*)d_in[8];

  char* ws = (char*)d_ws;
  size_t off = 0;
  auto alloc = [&](size_t n) { void* p = ws + off; off += (n + 255) & ~(size_t)255; return p; };
  bf16* xb   = (bf16*)alloc((size_t)Mm * Dd * 2);
  bf16* wqb  = (bf16*)alloc((size_t)Dd * Dd * 2);
  bf16* wkb  = (bf16*)alloc((size_t)Dd * Dd * 2);
  bf16* wvb  = (bf16*)alloc((size_t)Dd * Dd * 2);
  bf16* wfb  = (bf16*)alloc((size_t)Dd * Dd * 2);
  bf16* Qb   = (bf16*)alloc((size_t)Mm * Dd * 2);
  bf16* Kb   = (bf16*)alloc((size_t)Mm * Dd * 2);
  bf16* Vtb  = (bf16*)alloc((size_t)Mm * Dd * 2);
  bf16* ctxb = (bf16*)alloc((size_t)Mm * Dd * 2);

  CastArgs ca;
  ca.src[0] = x;  ca.dst[0] = xb;  int n0 = Mm * Dd / 4;
  ca.src[1] = Wq; ca.dst[1] = wqb; int nw = Dd * Dd / 4;
  ca.src[2] = Wk; ca.dst[2] = wkb;
  ca.src[3] = Wv; ca.dst[3] = wvb;
  ca.src[4] = Wf; ca.dst[4] = wfb;
  ca.cum[0] = n0; ca.cum[1] = n0 + nw; ca.cum[2] = n0 + 2 * nw;
  ca.cum[3] = n0 + 3 * nw; ca.cum[4] = n0 + 4 * nw;
  int tot = ca.cum[4];
  cast_all<<<(tot + 255) / 256, 256, 0, stream>>>(ca, tot);

  gemm_qkv<<<dim3(64 * 8 * 3), 256, 0, stream>>>(xb, wqb, wkb, wvb, bq, bk, bv, Qb, Kb, Vtb);

  float* probs = (float*)d_out + (size_t)Mm * Dd;
  attn_fused<<<dim3(Bb * Hh * 8), 512, 0, stream>>>(Qb, Kb, Vtb, probs, ctxb);

  gemm_out<<<dim3(64 * 8), 256, 0, stream>>>(ctxb, wfb, bfp, (float*)d_out);
}

// Round 13
// 261.971 us; speedup vs baseline: 1.1012x; 1.0656x over previous
//
#include <hip/hip_runtime.h>

typedef __bf16 bf16;
typedef __bf16 bf16x4 __attribute__((ext_vector_type(4)));
typedef __bf16 bf16x8 __attribute__((ext_vector_type(8)));
typedef float  f32x4  __attribute__((ext_vector_type(4)));

constexpr int Bb = 8, Ss = 1024, Dd = 1024, Hh = 16, HDd = 64;
constexpr int Mm = Bb * Ss;   // 8192
constexpr int Kk = 1024;

#define WAITV(n) asm volatile("s_waitcnt vmcnt(" #n ")" ::: "memory")
#define PHASE_BAR { __builtin_amdgcn_s_barrier(); __builtin_amdgcn_sched_barrier(0); }

// ---------------- fused cast f32 -> bf16 (5 segments, float4 chunks) ----------------
struct CastArgs {
  const float* src[5];
  bf16* dst[5];
  int cum[5];
};
__global__ void cast_all(CastArgs a, int tot) {
  int i = blockIdx.x * blockDim.x + threadIdx.x;
  if (i >= tot) return;
  int s, base;
  if (i < a.cum[0])      { s = 0; base = 0; }
  else if (i < a.cum[1]) { s = 1; base = a.cum[0]; }
  else if (i < a.cum[2]) { s = 2; base = a.cum[1]; }
  else if (i < a.cum[3]) { s = 3; base = a.cum[2]; }
  else                   { s = 4; base = a.cum[3]; }
  int j = i - base;
  float4 v = reinterpret_cast<const float4*>(a.src[s])[j];
  bf16x4 o = { (bf16)v.x, (bf16)v.y, (bf16)v.z, (bf16)v.w };
  reinterpret_cast<bf16x4*>(a.dst[s])[j] = o;
}

// ---------------- 128x128 2-barrier GEMM core (verified) ----------------
__device__ __forceinline__ void gemm_loop(const bf16* __restrict__ A, const bf16* __restrict__ Bm,
                                          int bm, int bn, unsigned char* As, unsigned char* Bs,
                                          int w, int lane, int l15, int g, f32x4 (&acc)[4][4]) {
  const bf16* srcA[4];
  const bf16* srcB[4];
#pragma unroll
  for (int i = 0; i < 4; ++i) {
    int gch = (w * 4 + i) * 64 + lane;  // chunk id 0..1023
    int r = gch >> 3, c = gch & 7, cs = c ^ (r & 7);
    srcA[i] = A  + (size_t)(bm * 128 + r) * Kk + cs * 8;
    srcB[i] = Bm + (size_t)(bn * 128 + r) * Kk + cs * 8;
  }
  for (int kt = 0; kt < Kk / 64; ++kt) {
    __syncthreads();
#pragma unroll
    for (int i = 0; i < 4; ++i) {
      __builtin_amdgcn_global_load_lds(
          (const __attribute__((address_space(1))) void*)(srcA[i] + kt * 64),
          (__attribute__((address_space(3))) void*)(As + (w * 4 + i) * 1024), 16, 0, 0);
      __builtin_amdgcn_global_load_lds(
          (const __attribute__((address_space(1))) void*)(srcB[i] + kt * 64),
          (__attribute__((address_space(3))) void*)(Bs + (w * 4 + i) * 1024), 16, 0, 0);
    }
    __syncthreads();
#pragma unroll
    for (int kk = 0; kk < 2; ++kk) {
      const int kb = kk * 64 + g * 16;
      bf16x8 af[4], bfr[4];
#pragma unroll
      for (int mi = 0; mi < 4; ++mi) {
        int row = ((w >> 1) * 64) + mi * 16 + l15;
        af[mi] = *reinterpret_cast<const bf16x8*>(As + row * 128 + (kb ^ ((row & 7) << 4)));
      }
#pragma unroll
      for (int ni = 0; ni < 4; ++ni) {
        int row = ((w & 1) * 64) + ni * 16 + l15;
        bfr[ni] = *reinterpret_cast<const bf16x8*>(Bs + row * 128 + (kb ^ ((row & 7) << 4)));
      }
#pragma unroll
      for (int mi = 0; mi < 4; ++mi)
#pragma unroll
        for (int ni = 0; ni < 4; ++ni)
          acc[mi][ni] = __builtin_amdgcn_mfma_f32_16x16x32_bf16(af[mi], bfr[ni], acc[mi][ni], 0, 0, 0);
    }
  }
}

// ---------------- fused QKV projection (1D grid, XCD-clustered; verified R10) ----------------
// All 24 (bn,z) blocks sharing one bm's A-panel run consecutively on ONE XCD.
// z=0: Q = (x@Wq^T + bq)*(0.125*log2e) -> [b,h,s,hd]; z=1: K; z=2: V^T -> [b,h,hd,s]
__global__ __launch_bounds__(256) void gemm_qkv(const bf16* __restrict__ x,
                                                const bf16* __restrict__ wq, const bf16* __restrict__ wk,
                                                const bf16* __restrict__ wv,
                                                const float* __restrict__ bq, const float* __restrict__ bk,
                                                const float* __restrict__ bv,
                                                bf16* __restrict__ Qo, bf16* __restrict__ Ko,
                                                bf16* __restrict__ Vto) {
  const int tid = threadIdx.x;
  const int lane = tid & 63;
  const int w = tid >> 6;
  const int l15 = lane & 15, g = lane >> 4;

  const int id = blockIdx.x;
  const int xcd = id & 7, slot = id >> 3;       // 192 slots per XCD
  const int bmg = slot / 24, rem = slot % 24;   // 8 bm-groups x 24 (bn,z)
  const int bmx = xcd * 8 + bmg;
  const int bnx = rem & 7;
  const int z = rem >> 3;

  const bf16* A; const bf16* Bm; int bm, bn;
  if (z < 2) { A = x; Bm = z ? wk : wq; bm = bmx; bn = bnx; }
  else       { A = wv; Bm = x;          bm = bnx; bn = bmx; }

  __shared__ __align__(16) unsigned char As[128 * 128];
  __shared__ __align__(16) unsigned char Bs[128 * 128];
  f32x4 acc[4][4] = {};
  gemm_loop(A, Bm, bm, bn, As, Bs, w, lane, l15, g, acc);

  const int wr = (w >> 1) * 64, wc = (w & 1) * 64;
  if (z < 2) {
    const float* bias = z ? bk : bq;
    bf16* out = z ? Ko : Qo;
    const float scale = z ? 1.f : 0.125f * 1.44269504088896340736f;
#pragma unroll
    for (int ni = 0; ni < 4; ++ni) {
      int col = bn * 128 + wc + ni * 16 + l15;
      float bv_ = bias[col];
#pragma unroll
      for (int mi = 0; mi < 4; ++mi)
#pragma unroll
        for (int r = 0; r < 4; ++r) {
          int row = bm * 128 + wr + mi * 16 + g * 4 + r;
          float val = (acc[mi][ni][r] + bv_) * scale;
          size_t adr = ((size_t)((row >> 10) * Hh + (col >> 6)) * Ss + (row & 1023)) * HDd + (col & 63);
          out[adr] = (bf16)val;
        }
    }
  } else {  // V^T: row = d-index, col = bs-index, bias per row
#pragma unroll
    for (int mi = 0; mi < 4; ++mi)
#pragma unroll
      for (int r = 0; r < 4; ++r) {
        int row = bm * 128 + wr + mi * 16 + g * 4 + r;
        float bv_ = bv[row];
#pragma unroll
        for (int ni = 0; ni < 4; ++ni) {
          int col = bn * 128 + wc + ni * 16 + l15;
          size_t adr = ((size_t)((col >> 10) * Hh + (row >> 6)) * HDd + (row & 63)) * Ss + (col & 1023);
          Vto[adr] = (bf16)(acc[mi][ni][r] + bv_);
        }
      }
  }
}

// ---------------- final projection (1D grid, XCD-clustered): out = ctx @ Wf^T + bf ----------------
__global__ __launch_bounds__(256) void gemm_out(const bf16* __restrict__ A, const bf16* __restrict__ Bm,
                                                const float* __restrict__ bias, float* __restrict__ out) {
  const int tid = threadIdx.x;
  const int lane = tid & 63;
  const int w = tid >> 6;
  const int l15 = lane & 15, g = lane >> 4;
  const int id = blockIdx.x;                    // 512 blocks
  const int xcd = id & 7, slot = id >> 3;       // 64 slots per XCD
  const int bm = xcd * 8 + (slot >> 3);
  const int bn = slot & 7;
  __shared__ __align__(16) unsigned char As[128 * 128];
  __shared__ __align__(16) unsigned char Bs[128 * 128];
  f32x4 acc[4][4] = {};
  gemm_loop(A, Bm, bm, bn, As, Bs, w, lane, l15, g, acc);
  const int wr = (w >> 1) * 64, wc = (w & 1) * 64;
#pragma unroll
  for (int ni = 0; ni < 4; ++ni) {
    int col = bn * 128 + wc + ni * 16 + l15;
    float bv_ = bias[col];
#pragma unroll
    for (int mi = 0; mi < 4; ++mi)
#pragma unroll
      for (int r = 0; r < 4; ++r) {
        int row = bm * 128 + wr + mi * 16 + g * 4 + r;
        out[(size_t)row * Dd + col] = acc[mi][ni][r] + bv_;
      }
  }
}

// ---------------- fused attention (R6 schedule + exp2 + R10 decode; verified best 261.5us) ----------------
__global__ __launch_bounds__(512, 4) void attn_fused(const bf16* __restrict__ Q,
                                                     const bf16* __restrict__ Kt,
                                                     const bf16* __restrict__ Vt,
                                                     float* __restrict__ probs,
                                                     bf16* __restrict__ ctx) {
  const int tid = threadIdx.x;
  const int lane = tid & 63;
  const int w = tid >> 6;
  const int l15 = lane & 15, g = lane >> 4;
  const int bid = blockIdx.x;
  const int bh = (bid & 7) * 16 + ((bid >> 3) & 15);  // same head -> same bid%8 -> same XCD
  const int qt = bid >> 7;
  const int q0 = qt * 128 + w * 16;

  __shared__ __align__(16) unsigned char KV[4][16384];  // p1: K rotation; p2: K slabs 0/1, V 2/3
  __shared__ __align__(16) bf16 Ps[8][16][40];          // per-wave P chunk (32 k + pad)

  bf16x8 qf0, qf1;
  {
    const bf16* qp = Q + ((size_t)bh * Ss + q0 + l15) * HDd + g * 8;
    qf0 = *reinterpret_cast<const bf16x8*>(qp);
    qf1 = *reinterpret_cast<const bf16x8*>(qp + 32);
  }
  const bf16* kbase = Kt + (size_t)bh * Ss * HDd;
  const bf16* vbase = Vt + (size_t)bh * HDd * Ss;

  const bf16* ksrc[2];
  const bf16* vsrc[2];
#pragma unroll
  for (int i = 0; i < 2; ++i) {
    int ch = i * 512 + tid;
    int kr = ch >> 3, kc = (ch & 7) ^ (kr & 7);
    ksrc[i] = kbase + (size_t)kr * HDd + kc * 8;
    int vr = ch >> 4, vc = (ch & 15) ^ (vr & 15);
    vsrc[i] = vbase + (size_t)vr * Ss + vc * 8;
  }

#define SK(slab, t)                                                                       \
  {                                                                                       \
    _Pragma("unroll") for (int i = 0; i < 2; ++i)                                         \
        __builtin_amdgcn_global_load_lds(                                                 \
            (const __attribute__((address_space(1))) void*)(ksrc[i] + (size_t)(t) * 128 * HDd), \
            (__attribute__((address_space(3))) void*)(KV[slab] + (i * 512 + w * 64) * 16),\
            16, 0, 0);                                                                    \
  }
#define SV(slab, t)                                                                       \
  {                                                                                       \
    _Pragma("unroll") for (int i = 0; i < 2; ++i)                                         \
        __builtin_amdgcn_global_load_lds(                                                 \
            (const __attribute__((address_space(1))) void*)(vsrc[i] + (t) * 128),         \
            (__attribute__((address_space(3))) void*)(KV[slab] + (i * 512 + w * 64) * 16),\
            16, 0, 0);                                                                    \
  }

  auto kread = [&](int slab, int nk, int half) -> bf16x8 {
    int row = nk * 16 + l15;
    int chunk = (half * 4 + g) ^ (l15 & 7);
    return *reinterpret_cast<const bf16x8*>(KV[slab] + row * 128 + chunk * 16);
  };
  auto vread = [&](int slab, int nkp, int ni) -> bf16x8 {
    int row = ni * 16 + l15;
    int chunk = (nkp * 4 + g) ^ l15;
    return *reinterpret_cast<const bf16x8*>(KV[slab] + row * 256 + chunk * 16);
  };

  // ---- pass 1: row sum of exp2(score) ----
  float lr0 = 0.f, lr1 = 0.f, lr2 = 0.f, lr3 = 0.f;
  SK(0, 0); SK(1, 1); SK(2, 2);
  __builtin_amdgcn_sched_barrier(0);
  WAITV(4);
  PHASE_BAR;
  for (int kt = 0; kt < 8; ++kt) {
    if (kt <= 4)      { SK((kt + 3) & 3, kt + 3); }
    else if (kt == 7) { SK(0, 0); SV(2, 0); }
    __builtin_amdgcn_sched_barrier(0);
    const int ks = kt & 3;
#pragma unroll
    for (int nk = 0; nk < 8; ++nk) {
      f32x4 sc = {0.f, 0.f, 0.f, 0.f};
      bf16x8 k0 = kread(ks, nk, 0), k1 = kread(ks, nk, 1);
      __builtin_amdgcn_s_setprio(1);
      sc = __builtin_amdgcn_mfma_f32_16x16x32_bf16(k0, qf0, sc, 0, 0, 0);
      sc = __builtin_amdgcn_mfma_f32_16x16x32_bf16(k1, qf1, sc, 0, 0, 0);
      __builtin_amdgcn_s_setprio(0);
      lr0 += __builtin_amdgcn_exp2f(sc[0]);
      lr1 += __builtin_amdgcn_exp2f(sc[1]);
      lr2 += __builtin_amdgcn_exp2f(sc[2]);
      lr3 += __builtin_amdgcn_exp2f(sc[3]);
    }
    if (kt <= 4)      { WAITV(4); }
    else if (kt == 5) { WAITV(2); }
    else              { WAITV(0); }
    PHASE_BAR;
  }
  float lsum = (lr0 + lr1) + (lr2 + lr3);
  lsum += __shfl_xor(lsum, 16, 64);
  lsum += __shfl_xor(lsum, 32, 64);
  const float rl = 1.f / lsum;

  float* const prow = probs + ((size_t)bh * Ss + q0 + l15) * Ss;
  f32x4 cacc[4] = {};

  // ---- pass 2 (ascending; K[kt] slab kt&1, V[kt] slab 2+(kt&1)) ----
  for (int kt = 0; kt < 8; ++kt) {
    if (kt < 7) { SK((kt + 1) & 1, kt + 1); SV(2 + ((kt + 1) & 1), kt + 1); }
    __builtin_amdgcn_sched_barrier(0);
    const int ks = kt & 1, vs = 2 + (kt & 1);
#pragma unroll
    for (int nkp = 0; nkp < 4; ++nkp) {
#pragma unroll
      for (int h = 0; h < 2; ++h) {
        int nk = nkp * 2 + h;
        f32x4 sc = {0.f, 0.f, 0.f, 0.f};
        bf16x8 k0 = kread(ks, nk, 0), k1 = kread(ks, nk, 1);
        __builtin_amdgcn_s_setprio(1);
        sc = __builtin_amdgcn_mfma_f32_16x16x32_bf16(k0, qf0, sc, 0, 0, 0);
        sc = __builtin_amdgcn_mfma_f32_16x16x32_bf16(k1, qf1, sc, 0, 0, 0);
        __builtin_amdgcn_s_setprio(0);
        f32x4 pv;
#pragma unroll
        for (int r = 0; r < 4; ++r) pv[r] = __builtin_amdgcn_exp2f(sc[r]) * rl;
        *reinterpret_cast<f32x4*>(prow + kt * 128 + nk * 16 + g * 4) = pv;
        bf16x4 pb = { (bf16)pv[0], (bf16)pv[1], (bf16)pv[2], (bf16)pv[3] };
        *reinterpret_cast<bf16x4*>(&Ps[w][l15][h * 16 + g * 4]) = pb;
      }
      bf16x8 pf = *reinterpret_cast<const bf16x8*>(&Ps[w][l15][g * 8]);
      bf16x8 vf0 = vread(vs, nkp, 0), vf1 = vread(vs, nkp, 1);
      bf16x8 vf2 = vread(vs, nkp, 2), vf3 = vread(vs, nkp, 3);
      __builtin_amdgcn_s_setprio(1);
      cacc[0] = __builtin_amdgcn_mfma_f32_16x16x32_bf16(pf, vf0, cacc[0], 0, 0, 0);
      cacc[1] = __builtin_amdgcn_mfma_f32_16x16x32_bf16(pf, vf1, cacc[1], 0, 0, 0);
      cacc[2] = __builtin_amdgcn_mfma_f32_16x16x32_bf16(pf, vf2, cacc[2], 0, 0, 0);
      cacc[3] = __builtin_amdgcn_mfma_f32_16x16x32_bf16(pf, vf3, cacc[3], 0, 0, 0);
      __builtin_amdgcn_s_setprio(0);
    }
    if (kt < 7) {
      WAITV(8);
      PHASE_BAR;
    }
  }
#undef SK
#undef SV

  const int bb = bh >> 4, hh = bh & 15;
#pragma unroll
  for (int ni = 0; ni < 4; ++ni)
#pragma unroll
    for (int r = 0; r < 4; ++r) {
      int q = q0 + g * 4 + r;
      ctx[((size_t)bb * Ss + q) * Dd + hh * 64 + ni * 16 + l15] = (bf16)cacc[ni][r];
    }
}

// ---------------- launch ----------------
extern "C" void kernel_launch(void* const* d_in, const int* in_sizes, int n_in,
                              void* d_out, int out_size, void* d_ws, size_t ws_size,
                              hipStream_t stream) {
  (void)in_sizes; (void)n_in; (void)out_size; (void)ws_size;
  const float* x   = (const float*)d_in[0];
  const float* Wq  = (const float*)d_in[1];
  const float* bq  = (const float*)d_in[2];
  const float* Wk  = (const float*)d_in[3];
  const float* bk  = (const float*)d_in[4];
  const float* Wv  = (const float*)d_in[5];
  const float* bv  = (const float*)d_in[6];
  const float* Wf  = (const float*)d_in[7];
  const float* bfp = (const float*)d_in[8];

  char* ws = (char*)d_ws;
  size_t off = 0;
  auto alloc = [&](size_t n) { void* p = ws + off; off += (n + 255) & ~(size_t)255; return p; };
  bf16* xb   = (bf16*)alloc((size_t)Mm * Dd * 2);
  bf16* wqb  = (bf16*)alloc((size_t)Dd * Dd * 2);
  bf16* wkb  = (bf16*)alloc((size_t)Dd * Dd * 2);
  bf16* wvb  = (bf16*)alloc((size_t)Dd * Dd * 2);
  bf16* wfb  = (bf16*)alloc((size_t)Dd * Dd * 2);
  bf16* Qb   = (bf16*)alloc((size_t)Mm * Dd * 2);
  bf16* Kb   = (bf16*)alloc((size_t)Mm * Dd * 2);
  bf16* Vtb  = (bf16*)alloc((size_t)Mm * Dd * 2);
  bf16* ctxb = (bf16*)alloc((size_t)Mm * Dd * 2);

  CastArgs ca;
  ca.src[0] = x;  ca.dst[0] = xb;  int n0 = Mm * Dd / 4;
  ca.src[1] = Wq; ca.dst[1] = wqb; int nw = Dd * Dd / 4;
  ca.src[2] = Wk; ca.dst[2] = wkb;
  ca.src[3] = Wv; ca.dst[3] = wvb;
  ca.src[4] = Wf; ca.dst[4] = wfb;
  ca.cum[0] = n0; ca.cum[1] = n0 + nw; ca.cum[2] = n0 + 2 * nw;
  ca.cum[3] = n0 + 3 * nw; ca.cum[4] = n0 + 4 * nw;
  int tot = ca.cum[4];
  cast_all<<<(tot + 255) / 256, 256, 0, stream>>>(ca, tot);

  gemm_qkv<<<dim3(64 * 8 * 3), 256, 0, stream>>>(xb, wqb, wkb, wvb, bq, bk, bv, Qb, Kb, Vtb);

  float* probs = (float*)d_out + (size_t)Mm * Dd;
  attn_fused<<<dim3(Bb * Hh * 8), 512, 0, stream>>>(Qb, Kb, Vtb, probs, ctxb);

  gemm_out<<<dim3(64 * 8), 256, 0, stream>>>(ctxb, wfb, bfp, (float*)d_out);
}